// Round 1
// 1029.094 us; speedup vs baseline: 1.4693x; 1.4693x over previous
//
#include <hip/hip_runtime.h>
#include <hip/hip_bf16.h>

typedef __attribute__((ext_vector_type(4))) float floatx4;
typedef __attribute__((ext_vector_type(8))) short short8;

static __device__ __forceinline__ float b2f(short s) {
    unsigned int u = ((unsigned int)(unsigned short)s) << 16;
    float f;
    __builtin_memcpy(&f, &u, 4);
    return f;
}
static __device__ __forceinline__ short f2b(float f) {
    __hip_bfloat16 h = __float2bfloat16(f);
    unsigned short u;
    __builtin_memcpy(&u, &h, 2);
    return (short)u;
}
// Async global->LDS, 16B per lane. LDS dest is wave-uniform base + lane*16 (HW).
static __device__ __forceinline__ void gll16(const void* g, void* l) {
    __builtin_amdgcn_global_load_lds(
        (const __attribute__((address_space(1))) unsigned int*)g,
        (__attribute__((address_space(3))) unsigned int*)l, 16, 0, 0);
}

// Writes flag=1 if buffer at `x` (32-bit words, starting at word `off`) looks like
// packed bf16, 0 if fp32.
__global__ void detect_dtype(const unsigned int* __restrict__ x, int off,
                             int* __restrict__ flag) {
    __shared__ int cnt[256];
    const int tid = threadIdx.x;
    const unsigned int w = x[off + tid];
    const unsigned int e = (w >> 7) & 0xFF;
    cnt[tid] = (e >= 110 && e <= 140) ? 1 : 0;
    __syncthreads();
    for (int s = 128; s > 0; s >>= 1) {
        if (tid < s) cnt[tid] += cnt[tid + s];
        __syncthreads();
    }
    if (tid == 0) *flag = (cnt[0] >= 160) ? 1 : 0;
}

// Convert (fp32 or bf16, per flag) -> packed bf16. n8 = elements/8.
__global__ __launch_bounds__(256) void to_bf16(const void* __restrict__ src,
                                               short* __restrict__ dst,
                                               const int* __restrict__ dflag,
                                               unsigned int n8) {
    const int isb = *dflag;
    const unsigned int i = blockIdx.x * 256 + threadIdx.x;
    if (i >= n8) return;
    const size_t e = (size_t)i * 8;
    if (isb) {
        *(short8*)(dst + e) = *(const short8*)((const short*)src + e);
    } else {
        const float4* sp = (const float4*)((const float*)src + e);
        const float4 f0 = sp[0], f1 = sp[1];
        short8 v;
        v[0] = f2b(f0.x); v[1] = f2b(f0.y); v[2] = f2b(f0.z); v[3] = f2b(f0.w);
        v[4] = f2b(f1.x); v[5] = f2b(f1.y); v[6] = f2b(f1.z); v[7] = f2b(f1.w);
        *(short8*)(dst + e) = v;
    }
}

// C[m,n] = sum_k A[m,k]*B[n,k]. m97 structure: 128x128 tile, BK=32, 256 thr
// (2x2 waves, each 4x4 MFMA 16x16x32), linear LDS [128][32], global_load_lds
// width=16 staging, 2 barriers per K-step.
// A: always bf16 (gll). B: bf16 via gll unless (b_dyn && !*dflag) -> fp32 reg-stage.
// Store: bf16 unless (out_dyn && !*dflag) -> fp32.
__global__ __launch_bounds__(256) void gemm_bt_f(const short* __restrict__ A,
                                                 const void* __restrict__ B,
                                                 void* __restrict__ C,
                                                 int M, int N, int K,
                                                 const int* __restrict__ dflag,
                                                 int b_dyn, int out_dyn) {
    __shared__ short As[128 * 32];
    __shared__ short Bs[128 * 32];
    const int isb = *dflag;
    const int b_bf = b_dyn ? isb : 1;
    const int tid = threadIdx.x;
    const int wave = tid >> 6, lane = tid & 63;
    const int quad = lane >> 4, l16 = lane & 15;
    const int wm = (wave >> 1) * 64, wn = (wave & 1) * 64;
    const int m0 = blockIdx.y * 128, n0 = blockIdx.x * 128;
    // gll staging: wave stages rows [wave*32, wave*32+32) of A and B; one
    // instruction covers 16 rows (64 lanes x 16B; row = lane>>2, col = (lane&3)*8).
    const int g_r = lane >> 2;
    const int g_c = (lane & 3) * 8;
    const short* agp = A + (size_t)(m0 + wave * 32 + g_r) * K + g_c;
    const short* bgp = (const short*)B + (size_t)(n0 + wave * 32 + g_r) * K + g_c;
    short* const asl0 = &As[(wave * 32) * 32];
    short* const asl1 = &As[(wave * 32 + 16) * 32];
    short* const bsl0 = &Bs[(wave * 32) * 32];
    short* const bsl1 = &Bs[(wave * 32 + 16) * 32];
    const size_t kstep16 = (size_t)16 * K;
    // fp32-B reg-staging coords: thread covers row tid>>1, 16 cols at (tid&1)*16.
    const int s_r = tid >> 1, s_c = (tid & 1) * 16;
    const size_t brow_f = (size_t)(n0 + s_r) * K + s_c;

    floatx4 acc[4][4] = {};
    for (int k0 = 0; k0 < K; k0 += 32) {
        gll16(agp + k0, asl0);
        gll16(agp + k0 + kstep16, asl1);
        if (b_bf) {
            gll16(bgp + k0, bsl0);
            gll16(bgp + k0 + kstep16, bsl1);
        } else {
            const float* bp = (const float*)B + brow_f + k0;
            const float4 f0 = ((const float4*)bp)[0], f1 = ((const float4*)bp)[1];
            const float4 f2 = ((const float4*)bp)[2], f3 = ((const float4*)bp)[3];
            short8 v0, v1;
            v0[0] = f2b(f0.x); v0[1] = f2b(f0.y); v0[2] = f2b(f0.z); v0[3] = f2b(f0.w);
            v0[4] = f2b(f1.x); v0[5] = f2b(f1.y); v0[6] = f2b(f1.z); v0[7] = f2b(f1.w);
            v1[0] = f2b(f2.x); v1[1] = f2b(f2.y); v1[2] = f2b(f2.z); v1[3] = f2b(f2.w);
            v1[4] = f2b(f3.x); v1[5] = f2b(f3.y); v1[6] = f2b(f3.z); v1[7] = f2b(f3.w);
            *(short8*)&Bs[s_r * 32 + s_c] = v0;
            *(short8*)&Bs[s_r * 32 + s_c + 8] = v1;
        }
        __syncthreads();   // drains vmcnt (gll completion) + lgkmcnt (ds_write)
        short8 af[4], bq[4];
#pragma unroll
        for (int i = 0; i < 4; i++)
            af[i] = *(const short8*)&As[(wm + i * 16 + l16) * 32 + quad * 8];
#pragma unroll
        for (int j = 0; j < 4; j++)
            bq[j] = *(const short8*)&Bs[(wn + j * 16 + l16) * 32 + quad * 8];
#pragma unroll
        for (int i = 0; i < 4; i++)
#pragma unroll
            for (int j = 0; j < 4; j++)
                acc[i][j] = __builtin_amdgcn_mfma_f32_16x16x32_bf16(af[i], bq[j], acc[i][j], 0, 0, 0);
        __syncthreads();   // protect LDS from next iteration's staging
    }
    // C/D layout: col = lane&15, row = quad*4 + reg (m89-verified)
#pragma unroll
    for (int i = 0; i < 4; i++)
#pragma unroll
        for (int j = 0; j < 4; j++)
#pragma unroll
            for (int rr = 0; rr < 4; rr++) {
                const size_t row = m0 + wm + i * 16 + quad * 4 + rr;
                const size_t col = n0 + wn + j * 16 + l16;
                const float v = acc[i][j][rr];
                if (out_dyn && !isb)
                    ((float*)C)[row * N + col] = v;
                else
                    ((short*)C)[row * N + col] = f2b(v);
            }
}

// In-place RoPE on Q [4096 tok x 32 h x 128] (row stride 4096) and K inside the
// fused KV buffer [4096 tok x (8 Kh | 8 Vh) x 128] (row stride 2048). freqs per fflag.
__global__ __launch_bounds__(256) void rope_kernel(short* __restrict__ Qb,
                                                   short* __restrict__ Kb,
                                                   const void* __restrict__ freqs,
                                                   const int* __restrict__ fflag) {
    const int isb = *fflag;
    const int idx = blockIdx.x * 256 + threadIdx.x;
    constexpr int QP = 4096 * 32 * 64;
    short* ptr;
    int t, p;
    if (idx < QP) {
        t = idx >> 11;
        const int rem = idx & 2047;
        p = rem & 63;
        ptr = Qb + (size_t)t * 4096 + (rem >> 6) * 128 + 2 * p;
    } else {
        const int i = idx - QP;
        t = i >> 9;
        const int rem = i & 511;
        p = rem & 63;
        ptr = Kb + (size_t)t * 2048 + (rem >> 6) * 128 + 2 * p;
    }
    const int fi = (t & 1023) * 64 + p;
    const float f = isb ? b2f(((const short*)freqs)[fi]) : ((const float*)freqs)[fi];
    float sv, cv;
    sincosf(f, &sv, &cv);
    const float a = b2f(ptr[0]);
    const float bb = b2f(ptr[1]);
    ptr[0] = f2b(a * cv - bb * sv);
    ptr[1] = f2b(a * sv + bb * cv);
}

// Flash attention, all-bf16 buffers. One block per (batch, q-head, 64-q tile).
// K/V live in the fused KV buffer with row stride 2048 (Vc = Kc + 1024).
__global__ __launch_bounds__(256) void attn_kernel(const short* __restrict__ Q,
                                                   const short* __restrict__ Kc,
                                                   const short* __restrict__ Vc,
                                                   short* __restrict__ AO) {
    constexpr int LQ = 136, LV = 72, LP = 72;
    __shared__ short Qs[64 * LQ];
    __shared__ short Ks[64 * LQ];
    __shared__ short Vts[128 * LV];
    __shared__ short Ps[64 * LP];
    const int tid = threadIdx.x;
    const int qt = blockIdx.x, h = blockIdx.y, b = blockIdx.z;
    const int kvh = h >> 2;
    const size_t tbase = (size_t)b * 1024;
    const int q0 = qt * 64;
    const int wave = tid >> 6, lane = tid & 63;
    const int quad = lane >> 4, l16 = lane & 15;
    const int sr = tid >> 2, sc = (tid & 3) * 32;
    {
        const short* src = Q + (tbase + q0 + sr) * 4096 + h * 128 + sc;
#pragma unroll
        for (int j = 0; j < 4; j++)
            *(short8*)&Qs[sr * LQ + sc + 8 * j] = *(const short8*)(src + 8 * j);
    }
    floatx4 o[8] = {};
    float mrow[4], lrow[4];
#pragma unroll
    for (int rr = 0; rr < 4; rr++) { mrow[rr] = -1.0e30f; lrow[rr] = 0.0f; }
    const float scale = 0.08838834764831845f;
    for (int kt = 0; kt <= qt; kt++) {
        if (kt > 0) __syncthreads();
        {
            const short* ksrc = Kc + (tbase + kt * 64 + sr) * 2048 + kvh * 128 + sc;
#pragma unroll
            for (int j = 0; j < 4; j++)
                *(short8*)&Ks[sr * LQ + sc + 8 * j] = *(const short8*)(ksrc + 8 * j);
            const short* vsrc = Vc + (tbase + kt * 64 + sr) * 2048 + kvh * 128 + sc;
            short vv[32];
#pragma unroll
            for (int j = 0; j < 4; j++)
                *(short8*)(vv + 8 * j) = *(const short8*)(vsrc + 8 * j);
#pragma unroll
            for (int e = 0; e < 32; e++)
                Vts[(sc + e) * LV + sr] = vv[e];
        }
        __syncthreads();
        short8 aq[4];
#pragma unroll
        for (int kk = 0; kk < 4; kk++)
            aq[kk] = *(const short8*)&Qs[(wave * 16 + l16) * LQ + kk * 32 + quad * 8];
        floatx4 s[4];
#pragma unroll
        for (int j = 0; j < 4; j++) {
            floatx4 acc = {};
#pragma unroll
            for (int kk = 0; kk < 4; kk++) {
                short8 bk = *(const short8*)&Ks[(j * 16 + l16) * LQ + kk * 32 + quad * 8];
                acc = __builtin_amdgcn_mfma_f32_16x16x32_bf16(aq[kk], bk, acc, 0, 0, 0);
            }
            s[j] = acc;
        }
        const int qrow = q0 + wave * 16 + quad * 4;
#pragma unroll
        for (int j = 0; j < 4; j++)
#pragma unroll
            for (int rr = 0; rr < 4; rr++) {
                const float v = s[j][rr] * scale;
                const int key = kt * 64 + j * 16 + l16;
                s[j][rr] = (key > qrow + rr) ? -1.0e9f : v;
            }
        float alpha[4];
#pragma unroll
        for (int rr = 0; rr < 4; rr++) {
            float mx = fmaxf(fmaxf(s[0][rr], s[1][rr]), fmaxf(s[2][rr], s[3][rr]));
#pragma unroll
            for (int off = 1; off < 16; off <<= 1)
                mx = fmaxf(mx, __shfl_xor(mx, off, 64));
            const float mnew = fmaxf(mrow[rr], mx);
            alpha[rr] = __expf(mrow[rr] - mnew);
            float rsum = 0.0f;
#pragma unroll
            for (int j = 0; j < 4; j++) {
                const float p = __expf(s[j][rr] - mnew);
                s[j][rr] = p;
                rsum += p;
            }
#pragma unroll
            for (int off = 1; off < 16; off <<= 1)
                rsum += __shfl_xor(rsum, off, 64);
            lrow[rr] = lrow[rr] * alpha[rr] + rsum;
            mrow[rr] = mnew;
        }
#pragma unroll
        for (int c = 0; c < 8; c++)
#pragma unroll
            for (int rr = 0; rr < 4; rr++)
                o[c][rr] *= alpha[rr];
#pragma unroll
        for (int j = 0; j < 4; j++)
#pragma unroll
            for (int rr = 0; rr < 4; rr++)
                Ps[(wave * 16 + quad * 4 + rr) * LP + j * 16 + l16] = f2b(s[j][rr]);
        __syncthreads();
        short8 ap[2];
        ap[0] = *(const short8*)&Ps[(wave * 16 + l16) * LP + quad * 8];
        ap[1] = *(const short8*)&Ps[(wave * 16 + l16) * LP + 32 + quad * 8];
#pragma unroll
        for (int c = 0; c < 8; c++) {
#pragma unroll
            for (int kk = 0; kk < 2; kk++) {
                short8 bv = *(const short8*)&Vts[(c * 16 + l16) * LV + kk * 32 + quad * 8];
                o[c] = __builtin_amdgcn_mfma_f32_16x16x32_bf16(ap[kk], bv, o[c], 0, 0, 0);
            }
        }
    }
    float invl[4];
#pragma unroll
    for (int rr = 0; rr < 4; rr++) invl[rr] = 1.0f / lrow[rr];
#pragma unroll
    for (int c = 0; c < 8; c++)
#pragma unroll
        for (int rr = 0; rr < 4; rr++) {
            const size_t row = tbase + q0 + wave * 16 + quad * 4 + rr;
            AO[row * 4096 + h * 128 + c * 16 + l16] = f2b(o[c][rr] * invl[rr]);
        }
}

extern "C" void kernel_launch(void* const* d_in, const int* in_sizes, int n_in,
                              void* d_out, int out_size, void* d_ws, size_t ws_size,
                              hipStream_t stream) {
    // inputs: x, wq, wk, wv, wo, freqs, mask(unused), starting_pos(unused)
    const void* x     = d_in[0];
    const void* wq    = d_in[1];
    const void* wk    = d_in[2];
    const void* wv    = d_in[3];
    const void* wo    = d_in[4];
    const void* wo_b  = d_in[4];
    const void* freqs = d_in[5];
    char* ws = (char*)d_ws;
    int* flag = (int*)ws;                        // flag[0]: x/weights, flag[1]: freqs
    short* KV = (short*)(ws + 256);              // fused K|V cache: [4096][2048] bf16 = 16777216 B
    short* WB = (short*)(ws + 256 + 16777216);   // weight bf16 scratch, 33554432 B; becomes AO
    short* AO = WB;                              // attn out [4096][4096] bf16 (WB dead by then)
    short* Qb = (short*)d_out;                   // Q bf16 in d_out lower half (dead pre-final-GEMM)
    short* Xb = (short*)d_out + 16777216;        // x bf16 in d_out upper half (dead pre-final-GEMM)

    detect_dtype<<<1, 256, 0, stream>>>((const unsigned int*)x, 0, flag);
    detect_dtype<<<1, 256, 0, stream>>>((const unsigned int*)freqs, 100, flag + 1);
    // one-time bf16 conversions (memory-bound, ~45us total)
    to_bf16<<<8192, 256, 0, stream>>>(x, Xb, flag, 2097152);
    to_bf16<<<8192, 256, 0, stream>>>(wq, WB, flag, 2097152);
    gemm_bt_f<<<dim3(32, 32), 256, 0, stream>>>(Xb, WB, Qb, 4096, 4096, 4096, flag, 0, 0);
    // fused K|V weights into one [2048][4096] B -> single N=2048 GEMM (2 blocks/CU)
    to_bf16<<<2048, 256, 0, stream>>>(wk, WB, flag, 524288);
    to_bf16<<<2048, 256, 0, stream>>>(wv, WB + 4194304, flag, 524288);
    gemm_bt_f<<<dim3(16, 32), 256, 0, stream>>>(Xb, WB, KV, 4096, 2048, 4096, flag, 0, 0);
    rope_kernel<<<40960, 256, 0, stream>>>(Qb, KV, freqs, flag + 1);
    attn_kernel<<<dim3(16, 32, 4), 256, 0, stream>>>(Qb, KV, KV + 1024, AO);
    // final GEMM: A=AO (bf16, gll), B=wo dynamic (reg-stage convert if fp32)
    gemm_bt_f<<<dim3(32, 32), 256, 0, stream>>>(AO, wo_b, d_out, 4096, 4096, 4096, flag, 1, 1);
}

// Round 2
// 816.125 us; speedup vs baseline: 1.8527x; 1.2610x over previous
//
#include <hip/hip_runtime.h>
#include <hip/hip_bf16.h>

typedef __attribute__((ext_vector_type(4))) float floatx4;
typedef __attribute__((ext_vector_type(8))) short short8;

static __device__ __forceinline__ float b2f(short s) {
    unsigned int u = ((unsigned int)(unsigned short)s) << 16;
    float f;
    __builtin_memcpy(&f, &u, 4);
    return f;
}
static __device__ __forceinline__ short f2b(float f) {
    __hip_bfloat16 h = __float2bfloat16(f);
    unsigned short u;
    __builtin_memcpy(&u, &h, 2);
    return (short)u;
}
// Async global->LDS, 16B per lane. LDS dest is wave-uniform base + lane*16 (HW).
static __device__ __forceinline__ void gll16(const void* g, void* l) {
    __builtin_amdgcn_global_load_lds(
        (const __attribute__((address_space(1))) unsigned int*)g,
        (__attribute__((address_space(3))) unsigned int*)l, 16, 0, 0);
}

// Writes flag=1 if buffer at `x` (32-bit words, starting at word `off`) looks like
// packed bf16, 0 if fp32.
__global__ void detect_dtype(const unsigned int* __restrict__ x, int off,
                             int* __restrict__ flag) {
    __shared__ int cnt[256];
    const int tid = threadIdx.x;
    const unsigned int w = x[off + tid];
    const unsigned int e = (w >> 7) & 0xFF;
    cnt[tid] = (e >= 110 && e <= 140) ? 1 : 0;
    __syncthreads();
    for (int s = 128; s > 0; s >>= 1) {
        if (tid < s) cnt[tid] += cnt[tid + s];
        __syncthreads();
    }
    if (tid == 0) *flag = (cnt[0] >= 160) ? 1 : 0;
}

// Convert (fp32 or bf16, per flag) -> packed bf16. n8 = elements/8.
__global__ __launch_bounds__(256) void to_bf16(const void* __restrict__ src,
                                               short* __restrict__ dst,
                                               const int* __restrict__ dflag,
                                               unsigned int n8) {
    const int isb = *dflag;
    const unsigned int i = blockIdx.x * 256 + threadIdx.x;
    if (i >= n8) return;
    const size_t e = (size_t)i * 8;
    if (isb) {
        *(short8*)(dst + e) = *(const short8*)((const short*)src + e);
    } else {
        const float4* sp = (const float4*)((const float*)src + e);
        const float4 f0 = sp[0], f1 = sp[1];
        short8 v;
        v[0] = f2b(f0.x); v[1] = f2b(f0.y); v[2] = f2b(f0.z); v[3] = f2b(f0.w);
        v[4] = f2b(f1.x); v[5] = f2b(f1.y); v[6] = f2b(f1.z); v[7] = f2b(f1.w);
        *(short8*)(dst + e) = v;
    }
}

// ---------------------------------------------------------------------------
// 256x256-tile 8-phase GEMM (C[m,n] = sum_k A[m,k]*B[n,k]); all-bf16 operands.
// 512 thr = 8 waves (2M x 4N), BK=64 as two 32-col k-panels, LDS 128KB:
// [2 dbuf][A|B][2 halves][kp][128][32] with st_16x32 XOR swizzle (bit5 ^= row bit3),
// applied via pre-swizzled global source (gll dest is linear) + swizzled ds_read.
// Fragment interleave: m-frag i -> tile row (2i+wm)*16, n-frag j -> tile col
// (4j+wn)*16, so C-quadrant (mh,nh) touches exactly A-half mh / B-half nh.
// Phase schedule per group g (computes K-tile g from buf g&1), snake order:
//   p1 (0,0): read A0+B0 frags; stage A1,B0 of tile g+1 -> other buf
//   p2 (0,1): read B1 frags
//   p3 (1,1): read A1 frags;   stage A0 of tile g+2 -> this buf (A0 free since p1)
//   p4 (1,0): stage B1 of tile g+2 -> this buf (B1 free since p2); vmcnt(4)
// Each phase: [reads/stages]; s_barrier; setprio(1); 16 MFMA; setprio(0); s_barrier.
// vmcnt(4) leaves exactly the last 2 halves (4 gll) in flight; every half is
// guaranteed complete one full phase before its first ds_read.
// ---------------------------------------------------------------------------
#define QUAD_MFMA(MH, NH)                                                       \
    _Pragma("unroll") for (int i_ = 0; i_ < 4; ++i_)                            \
    _Pragma("unroll") for (int j_ = 0; j_ < 2; ++j_)                            \
    _Pragma("unroll") for (int kp_ = 0; kp_ < 2; ++kp_)                         \
        acc[(MH)*4 + i_][(NH)*2 + j_] = __builtin_amdgcn_mfma_f32_16x16x32_bf16(\
            aF[i_][kp_], bF[NH][j_][kp_], acc[(MH)*4 + i_][(NH)*2 + j_], 0, 0, 0);

#define READ_A(BUFP, MH)                                                        \
    _Pragma("unroll") for (int i_ = 0; i_ < 4; ++i_) {                          \
        const int r_ = (2 * i_ + wm) * 16 + l16;                                \
        _Pragma("unroll") for (int kp_ = 0; kp_ < 2; ++kp_)                     \
            aF[i_][kp_] = *(const short8*)&(BUFP)[(MH)*8192 + kp_*4096 + r_*32 + swzc]; \
    }

#define READ_B(BUFP, NH)                                                        \
    _Pragma("unroll") for (int j_ = 0; j_ < 2; ++j_) {                          \
        const int r_ = (4 * j_ + wn) * 16 + l16;                                \
        _Pragma("unroll") for (int kp_ = 0; kp_ < 2; ++kp_)                     \
            bF[NH][j_][kp_] = *(const short8*)&(BUFP)[16384 + (NH)*8192 + kp_*4096 + r_*32 + swzc]; \
    }

// Stage one 128x64 half-tile: 2 gll per wave (kp=0,1); wave w covers rows w*16..+15.
#define STAGE(BUFP, OPOFF, GBASE, ROW0, TT)                                     \
    {                                                                           \
        const short* g_ = (GBASE) + (size_t)((ROW0) + wave * 16 + (lane >> 2)) * K \
                          + (TT) * 64 + scol;                                   \
        gll16(g_, (BUFP) + (OPOFF) + wave * 512);                               \
        gll16(g_ + 32, (BUFP) + (OPOFF) + 4096 + wave * 512);                   \
    }

__global__ __launch_bounds__(512, 2) void gemm256(const short* __restrict__ A,
                                                  const short* __restrict__ B,
                                                  void* __restrict__ C,
                                                  int M, int N, int K,
                                                  const int* __restrict__ dflag,
                                                  int out_dyn) {
    __shared__ short lds[65536];  // 128 KB: [buf:32768][op:16384][half:8192] shorts
    const int isb = *dflag;
    const int tid = threadIdx.x;
    const int wave = tid >> 6, lane = tid & 63;
    const int wm = wave >> 2, wn = wave & 3;
    const int quad = lane >> 4, l16 = lane & 15;
    // XCD-aware swizzle (nwg % 8 == 0 for all our launches)
    const int nwg = gridDim.x * gridDim.y;
    int lin = blockIdx.y * gridDim.x + blockIdx.x;
    lin = (lin & 7) * (nwg >> 3) + (lin >> 3);
    const int m0 = (lin / gridDim.x) * 256, n0 = (lin % gridDim.x) * 256;
    // swizzled read column (shorts): quad*8 XOR (row-bit3 -> +16 shorts = 32B)
    const int swzc = (quad * 8) ^ ((l16 & 8) << 1);
    // pre-swizzled global source column for staging (inverse of read swizzle)
    const int scol = ((lane & 3) * 8) ^ (((lane >> 5) & 1) << 4);
    const int NG = K >> 6;

    floatx4 acc[8][4] = {};
    short8 aF[4][2], bF[2][2][2];

    // ---- prologue: tile0 fully -> buf0; A0,B1 of tile1 -> buf1
    {
        const int t1p = (1 < NG) ? 1 : NG - 1;
        STAGE(lds, 0, A, m0, 0);                       // A half0
        STAGE(lds, 16384, B, n0, 0);                   // B half0
        STAGE(lds, 16384 + 8192, B, n0 + 128, 0);      // B half1
        STAGE(lds, 8192, A, m0 + 128, 0);              // A half1
        STAGE(lds + 32768, 0, A, m0, t1p);             // A0(tile1)
        STAGE(lds + 32768, 16384 + 8192, B, n0 + 128, t1p);  // B1(tile1)
    }
    asm volatile("s_waitcnt vmcnt(4)" ::: "memory");   // tile0 complete
    __builtin_amdgcn_s_barrier();
    __builtin_amdgcn_sched_barrier(0);

    for (int g = 0; g < NG; ++g) {
        short* bufc = lds + (g & 1) * 32768;
        short* bufn = lds + ((g + 1) & 1) * 32768;
        const int t1 = (g + 1 < NG) ? g + 1 : NG - 1;
        const int t2 = (g + 2 < NG) ? g + 2 : NG - 1;
        // ---- phase 1: quadrant (0,0)
        READ_A(bufc, 0);
        READ_B(bufc, 0);
        STAGE(bufn, 8192, A, m0 + 128, t1);            // A1(g+1)
        STAGE(bufn, 16384, B, n0, t1);                 // B0(g+1)
        __builtin_amdgcn_s_barrier();
        __builtin_amdgcn_s_setprio(1);
        QUAD_MFMA(0, 0);
        __builtin_amdgcn_s_setprio(0);
        __builtin_amdgcn_s_barrier();
        // ---- phase 2: quadrant (0,1)
        READ_B(bufc, 1);
        __builtin_amdgcn_s_barrier();
        __builtin_amdgcn_s_setprio(1);
        QUAD_MFMA(0, 1);
        __builtin_amdgcn_s_setprio(0);
        __builtin_amdgcn_s_barrier();
        // ---- phase 3: quadrant (1,1)
        READ_A(bufc, 1);
        STAGE(bufc, 0, A, m0, t2);                     // A0(g+2), region free since p1
        __builtin_amdgcn_s_barrier();
        __builtin_amdgcn_s_setprio(1);
        QUAD_MFMA(1, 1);
        __builtin_amdgcn_s_setprio(0);
        __builtin_amdgcn_s_barrier();
        // ---- phase 4: quadrant (1,0) (B0 frags still live in regs from p1)
        STAGE(bufc, 16384 + 8192, B, n0 + 128, t2);    // B1(g+2), region free since p2
        asm volatile("s_waitcnt vmcnt(4)" ::: "memory");  // tile g+1 complete
        __builtin_amdgcn_s_barrier();
        __builtin_amdgcn_sched_barrier(0);
        __builtin_amdgcn_s_setprio(1);
        QUAD_MFMA(1, 0);
        __builtin_amdgcn_s_setprio(0);
        __builtin_amdgcn_s_barrier();
    }
    asm volatile("s_waitcnt vmcnt(0)" ::: "memory");   // drain dead tail stages

    // C/D layout: col = lane&15, row = quad*4 + reg (m89-verified)
#pragma unroll
    for (int i = 0; i < 8; ++i)
#pragma unroll
        for (int j = 0; j < 4; ++j)
#pragma unroll
            for (int rr = 0; rr < 4; ++rr) {
                const size_t row = m0 + (2 * i + wm) * 16 + quad * 4 + rr;
                const size_t col = n0 + (4 * j + wn) * 16 + l16;
                const float v = acc[i][j][rr];
                if (out_dyn && !isb)
                    ((float*)C)[row * N + col] = v;
                else
                    ((short*)C)[row * N + col] = f2b(v);
            }
}

// Fallback 128x128 GEMM (handles fp32 B via reg-stage); used for the final
// projection only when ws_size is too small to pre-convert wo.
__global__ __launch_bounds__(256) void gemm_bt_f(const short* __restrict__ A,
                                                 const void* __restrict__ B,
                                                 void* __restrict__ C,
                                                 int M, int N, int K,
                                                 const int* __restrict__ dflag,
                                                 int b_dyn, int out_dyn) {
    __shared__ short As[128 * 32];
    __shared__ short Bs[128 * 32];
    const int isb = *dflag;
    const int b_bf = b_dyn ? isb : 1;
    const int tid = threadIdx.x;
    const int wave = tid >> 6, lane = tid & 63;
    const int quad = lane >> 4, l16 = lane & 15;
    const int wm = (wave >> 1) * 64, wn = (wave & 1) * 64;
    const int m0 = blockIdx.y * 128, n0 = blockIdx.x * 128;
    const int g_r = lane >> 2;
    const int g_c = (lane & 3) * 8;
    const short* agp = A + (size_t)(m0 + wave * 32 + g_r) * K + g_c;
    const short* bgp = (const short*)B + (size_t)(n0 + wave * 32 + g_r) * K + g_c;
    short* const asl0 = &As[(wave * 32) * 32];
    short* const asl1 = &As[(wave * 32 + 16) * 32];
    short* const bsl0 = &Bs[(wave * 32) * 32];
    short* const bsl1 = &Bs[(wave * 32 + 16) * 32];
    const size_t kstep16 = (size_t)16 * K;
    const int s_r = tid >> 1, s_c = (tid & 1) * 16;
    const size_t brow_f = (size_t)(n0 + s_r) * K + s_c;

    floatx4 acc[4][4] = {};
    for (int k0 = 0; k0 < K; k0 += 32) {
        gll16(agp + k0, asl0);
        gll16(agp + k0 + kstep16, asl1);
        if (b_bf) {
            gll16(bgp + k0, bsl0);
            gll16(bgp + k0 + kstep16, bsl1);
        } else {
            const float* bp = (const float*)B + brow_f + k0;
            const float4 f0 = ((const float4*)bp)[0], f1 = ((const float4*)bp)[1];
            const float4 f2 = ((const float4*)bp)[2], f3 = ((const float4*)bp)[3];
            short8 v0, v1;
            v0[0] = f2b(f0.x); v0[1] = f2b(f0.y); v0[2] = f2b(f0.z); v0[3] = f2b(f0.w);
            v0[4] = f2b(f1.x); v0[5] = f2b(f1.y); v0[6] = f2b(f1.z); v0[7] = f2b(f1.w);
            v1[0] = f2b(f2.x); v1[1] = f2b(f2.y); v1[2] = f2b(f2.z); v1[3] = f2b(f2.w);
            v1[4] = f2b(f3.x); v1[5] = f2b(f3.y); v1[6] = f2b(f3.z); v1[7] = f2b(f3.w);
            *(short8*)&Bs[s_r * 32 + s_c] = v0;
            *(short8*)&Bs[s_r * 32 + s_c + 8] = v1;
        }
        __syncthreads();
        short8 af[4], bq[4];
#pragma unroll
        for (int i = 0; i < 4; i++)
            af[i] = *(const short8*)&As[(wm + i * 16 + l16) * 32 + quad * 8];
#pragma unroll
        for (int j = 0; j < 4; j++)
            bq[j] = *(const short8*)&Bs[(wn + j * 16 + l16) * 32 + quad * 8];
#pragma unroll
        for (int i = 0; i < 4; i++)
#pragma unroll
            for (int j = 0; j < 4; j++)
                acc[i][j] = __builtin_amdgcn_mfma_f32_16x16x32_bf16(af[i], bq[j], acc[i][j], 0, 0, 0);
        __syncthreads();
    }
#pragma unroll
    for (int i = 0; i < 4; i++)
#pragma unroll
        for (int j = 0; j < 4; j++)
#pragma unroll
            for (int rr = 0; rr < 4; rr++) {
                const size_t row = m0 + wm + i * 16 + quad * 4 + rr;
                const size_t col = n0 + wn + j * 16 + l16;
                const float v = acc[i][j][rr];
                if (out_dyn && !isb)
                    ((float*)C)[row * N + col] = v;
                else
                    ((short*)C)[row * N + col] = f2b(v);
            }
}

// In-place RoPE on Q [4096 tok x 32 h x 128] (row stride 4096) and K inside the
// fused KV buffer [4096 tok x (8 Kh | 8 Vh) x 128] (row stride 2048).
__global__ __launch_bounds__(256) void rope_kernel(short* __restrict__ Qb,
                                                   short* __restrict__ Kb,
                                                   const void* __restrict__ freqs,
                                                   const int* __restrict__ fflag) {
    const int isb = *fflag;
    const int idx = blockIdx.x * 256 + threadIdx.x;
    constexpr int QP = 4096 * 32 * 64;
    short* ptr;
    int t, p;
    if (idx < QP) {
        t = idx >> 11;
        const int rem = idx & 2047;
        p = rem & 63;
        ptr = Qb + (size_t)t * 4096 + (rem >> 6) * 128 + 2 * p;
    } else {
        const int i = idx - QP;
        t = i >> 9;
        const int rem = i & 511;
        p = rem & 63;
        ptr = Kb + (size_t)t * 2048 + (rem >> 6) * 128 + 2 * p;
    }
    const int fi = (t & 1023) * 64 + p;
    const float f = isb ? b2f(((const short*)freqs)[fi]) : ((const float*)freqs)[fi];
    float sv, cv;
    sincosf(f, &sv, &cv);
    const float a = b2f(ptr[0]);
    const float bb = b2f(ptr[1]);
    ptr[0] = f2b(a * cv - bb * sv);
    ptr[1] = f2b(a * sv + bb * cv);
}

// Flash attention, all-bf16 buffers. One block per (batch, q-head, 64-q tile).
// K/V live in the fused KV buffer with row stride 2048 (Vc = Kc + 1024).
__global__ __launch_bounds__(256) void attn_kernel(const short* __restrict__ Q,
                                                   const short* __restrict__ Kc,
                                                   const short* __restrict__ Vc,
                                                   short* __restrict__ AO) {
    constexpr int LQ = 136, LV = 72, LP = 72;
    __shared__ short Qs[64 * LQ];
    __shared__ short Ks[64 * LQ];
    __shared__ short Vts[128 * LV];
    __shared__ short Ps[64 * LP];
    const int tid = threadIdx.x;
    const int qt = blockIdx.x, h = blockIdx.y, b = blockIdx.z;
    const int kvh = h >> 2;
    const size_t tbase = (size_t)b * 1024;
    const int q0 = qt * 64;
    const int wave = tid >> 6, lane = tid & 63;
    const int quad = lane >> 4, l16 = lane & 15;
    const int sr = tid >> 2, sc = (tid & 3) * 32;
    {
        const short* src = Q + (tbase + q0 + sr) * 4096 + h * 128 + sc;
#pragma unroll
        for (int j = 0; j < 4; j++)
            *(short8*)&Qs[sr * LQ + sc + 8 * j] = *(const short8*)(src + 8 * j);
    }
    floatx4 o[8] = {};
    float mrow[4], lrow[4];
#pragma unroll
    for (int rr = 0; rr < 4; rr++) { mrow[rr] = -1.0e30f; lrow[rr] = 0.0f; }
    const float scale = 0.08838834764831845f;
    for (int kt = 0; kt <= qt; kt++) {
        if (kt > 0) __syncthreads();
        {
            const short* ksrc = Kc + (tbase + kt * 64 + sr) * 2048 + kvh * 128 + sc;
#pragma unroll
            for (int j = 0; j < 4; j++)
                *(short8*)&Ks[sr * LQ + sc + 8 * j] = *(const short8*)(ksrc + 8 * j);
            const short* vsrc = Vc + (tbase + kt * 64 + sr) * 2048 + kvh * 128 + sc;
            short vv[32];
#pragma unroll
            for (int j = 0; j < 4; j++)
                *(short8*)(vv + 8 * j) = *(const short8*)(vsrc + 8 * j);
#pragma unroll
            for (int e = 0; e < 32; e++)
                Vts[(sc + e) * LV + sr] = vv[e];
        }
        __syncthreads();
        short8 aq[4];
#pragma unroll
        for (int kk = 0; kk < 4; kk++)
            aq[kk] = *(const short8*)&Qs[(wave * 16 + l16) * LQ + kk * 32 + quad * 8];
        floatx4 s[4];
#pragma unroll
        for (int j = 0; j < 4; j++) {
            floatx4 acc = {};
#pragma unroll
            for (int kk = 0; kk < 4; kk++) {
                short8 bk = *(const short8*)&Ks[(j * 16 + l16) * LQ + kk * 32 + quad * 8];
                acc = __builtin_amdgcn_mfma_f32_16x16x32_bf16(aq[kk], bk, acc, 0, 0, 0);
            }
            s[j] = acc;
        }
        const int qrow = q0 + wave * 16 + quad * 4;
#pragma unroll
        for (int j = 0; j < 4; j++)
#pragma unroll
            for (int rr = 0; rr < 4; rr++) {
                const float v = s[j][rr] * scale;
                const int key = kt * 64 + j * 16 + l16;
                s[j][rr] = (key > qrow + rr) ? -1.0e9f : v;
            }
        float alpha[4];
#pragma unroll
        for (int rr = 0; rr < 4; rr++) {
            float mx = fmaxf(fmaxf(s[0][rr], s[1][rr]), fmaxf(s[2][rr], s[3][rr]));
#pragma unroll
            for (int off = 1; off < 16; off <<= 1)
                mx = fmaxf(mx, __shfl_xor(mx, off, 64));
            const float mnew = fmaxf(mrow[rr], mx);
            alpha[rr] = __expf(mrow[rr] - mnew);
            float rsum = 0.0f;
#pragma unroll
            for (int j = 0; j < 4; j++) {
                const float p = __expf(s[j][rr] - mnew);
                s[j][rr] = p;
                rsum += p;
            }
#pragma unroll
            for (int off = 1; off < 16; off <<= 1)
                rsum += __shfl_xor(rsum, off, 64);
            lrow[rr] = lrow[rr] * alpha[rr] + rsum;
            mrow[rr] = mnew;
        }
#pragma unroll
        for (int c = 0; c < 8; c++)
#pragma unroll
            for (int rr = 0; rr < 4; rr++)
                o[c][rr] *= alpha[rr];
#pragma unroll
        for (int j = 0; j < 4; j++)
#pragma unroll
            for (int rr = 0; rr < 4; rr++)
                Ps[(wave * 16 + quad * 4 + rr) * LP + j * 16 + l16] = f2b(s[j][rr]);
        __syncthreads();
        short8 ap[2];
        ap[0] = *(const short8*)&Ps[(wave * 16 + l16) * LP + quad * 8];
        ap[1] = *(const short8*)&Ps[(wave * 16 + l16) * LP + 32 + quad * 8];
#pragma unroll
        for (int c = 0; c < 8; c++) {
#pragma unroll
            for (int kk = 0; kk < 2; kk++) {
                short8 bv = *(const short8*)&Vts[(c * 16 + l16) * LV + kk * 32 + quad * 8];
                o[c] = __builtin_amdgcn_mfma_f32_16x16x32_bf16(ap[kk], bv, o[c], 0, 0, 0);
            }
        }
    }
    float invl[4];
#pragma unroll
    for (int rr = 0; rr < 4; rr++) invl[rr] = 1.0f / lrow[rr];
#pragma unroll
    for (int c = 0; c < 8; c++)
#pragma unroll
        for (int rr = 0; rr < 4; rr++) {
            const size_t row = tbase + q0 + wave * 16 + quad * 4 + rr;
            AO[row * 4096 + h * 128 + c * 16 + l16] = f2b(o[c][rr] * invl[rr]);
        }
}

extern "C" void kernel_launch(void* const* d_in, const int* in_sizes, int n_in,
                              void* d_out, int out_size, void* d_ws, size_t ws_size,
                              hipStream_t stream) {
    // inputs: x, wq, wk, wv, wo, freqs, mask(unused), starting_pos(unused)
    const void* x     = d_in[0];
    const void* wq    = d_in[1];
    const void* wk    = d_in[2];
    const void* wv    = d_in[3];
    const void* wo    = d_in[4];
    const void* freqs = d_in[5];
    char* ws = (char*)d_ws;
    int* flag = (int*)ws;                        // flag[0]: x/weights, flag[1]: freqs
    short* KV = (short*)(ws + 256);              // fused K|V cache: [4096][2048] bf16 = 16 MB
    short* WB = (short*)(ws + 256 + 16777216);   // weight bf16 scratch 32 MB; becomes AO
    short* AO = WB;                              // attn out [4096][4096] bf16
    short* WOB = (short*)(ws + 256 + 16777216 + 33554432);  // wo bf16 (only if ws allows)
    short* Qb = (short*)d_out;                   // Q bf16 in d_out lower half
    short* Xb = (short*)d_out + 16777216;        // x bf16 in d_out upper half
    const bool big_ws = ws_size >= (size_t)(256 + 16777216 + 33554432 + 33554432);

    detect_dtype<<<1, 256, 0, stream>>>((const unsigned int*)x, 0, flag);
    detect_dtype<<<1, 256, 0, stream>>>((const unsigned int*)freqs, 100, flag + 1);
    // one-time bf16 conversions (memory-bound)
    to_bf16<<<8192, 256, 0, stream>>>(x, Xb, flag, 2097152);
    to_bf16<<<8192, 256, 0, stream>>>(wq, WB, flag, 2097152);
    gemm256<<<dim3(16, 16), 512, 0, stream>>>(Xb, WB, Qb, 4096, 4096, 4096, flag, 0);
    // fused K|V weights into one [2048][4096] B -> single N=2048 GEMM
    to_bf16<<<2048, 256, 0, stream>>>(wk, WB, flag, 524288);
    to_bf16<<<2048, 256, 0, stream>>>(wv, WB + 4194304, flag, 524288);
    gemm256<<<dim3(8, 16), 512, 0, stream>>>(Xb, WB, KV, 4096, 2048, 4096, flag, 0);
    rope_kernel<<<40960, 256, 0, stream>>>(Qb, KV, freqs, flag + 1);
    attn_kernel<<<dim3(16, 32, 4), 256, 0, stream>>>(Qb, KV, KV + 1024, AO);
    if (big_ws) {
        to_bf16<<<8192, 256, 0, stream>>>(wo, WOB, flag, 2097152);
        gemm256<<<dim3(16, 16), 512, 0, stream>>>(AO, WOB, d_out, 4096, 4096, 4096, flag, 1);
    } else {
        gemm_bt_f<<<dim3(32, 32), 256, 0, stream>>>(AO, wo, d_out, 4096, 4096, 4096, flag, 1, 1);
    }
}